// Round 1
// baseline (405.440 us; speedup 1.0000x reference)
//
#include <hip/hip_runtime.h>
#include <hip/hip_bf16.h>

// ---------------------------------------------------------------------------
// Sizes (fixed for this problem)
// ---------------------------------------------------------------------------
#define BATCH 4
#define NN    256      // nodes
#define DD    600      // feature/mem dim
#define HH    256      // attn hidden
#define MROWS (BATCH*NN)   // 1024

// ---------------------------------------------------------------------------
// Generic fp32 tiled GEMM: C = A[M,K] @ B[K,N] (+bias) (+relu), batched via z
// A ld = K, B ld = ldb, C ld = N.
// ---------------------------------------------------------------------------
#define BM 32
#define BN 32
#define BK 16

template<bool BIAS, bool RELU>
__global__ __launch_bounds__(256) void gemm_f32(
    const float* __restrict__ A, const float* __restrict__ B,
    const float* __restrict__ bias, float* __restrict__ C,
    int M, int N, int K, int ldb,
    long long sA, long long sB, long long sC)
{
    __shared__ float As[BM][BK + 1];
    __shared__ float Bs[BK][BN + 1];

    const int bz = blockIdx.z;
    A += (long long)bz * sA;
    B += (long long)bz * sB;
    C += (long long)bz * sC;

    const int row0 = blockIdx.y * BM;
    const int col0 = blockIdx.x * BN;
    const int tid  = threadIdx.x;
    const int tx = tid & 15;        // 0..15  (cols /2)
    const int ty = tid >> 4;        // 0..15  (rows /2)

    float acc[2][2] = {{0.f, 0.f}, {0.f, 0.f}};

    for (int k0 = 0; k0 < K; k0 += BK) {
        // load A tile (BM x BK = 512 elems, 2 per thread)
        #pragma unroll
        for (int i = 0; i < 2; ++i) {
            int e  = tid + i * 256;
            int ar = e >> 4, ak = e & 15;
            int gr = row0 + ar, gk = k0 + ak;
            As[ar][ak] = (gr < M && gk < K) ? A[(long long)gr * K + gk] : 0.f;
        }
        // load B tile (BK x BN = 512 elems, 2 per thread)
        #pragma unroll
        for (int i = 0; i < 2; ++i) {
            int e  = tid + i * 256;
            int bk = e >> 5, bc = e & 31;
            int gk = k0 + bk, gc = col0 + bc;
            Bs[bk][bc] = (gk < K && gc < N) ? B[(long long)gk * ldb + gc] : 0.f;
        }
        __syncthreads();
        #pragma unroll
        for (int kk = 0; kk < BK; ++kk) {
            float a0 = As[ty * 2][kk];
            float a1 = As[ty * 2 + 1][kk];
            float b0 = Bs[kk][tx * 2];
            float b1 = Bs[kk][tx * 2 + 1];
            acc[0][0] += a0 * b0;
            acc[0][1] += a0 * b1;
            acc[1][0] += a1 * b0;
            acc[1][1] += a1 * b1;
        }
        __syncthreads();
    }

    #pragma unroll
    for (int i = 0; i < 2; ++i) {
        #pragma unroll
        for (int j = 0; j < 2; ++j) {
            int r = row0 + ty * 2 + i;
            int c = col0 + tx * 2 + j;
            if (r < M && c < N) {
                float v = acc[i][j];
                if (BIAS) v += bias[c];
                if (RELU) v = fmaxf(v, 0.f);
                C[(long long)r * N + c] = v;
            }
        }
    }
}

// ---------------------------------------------------------------------------
// Transpose right[B, N(j), H] -> rightT[B, H, N(j)]
// ---------------------------------------------------------------------------
__global__ __launch_bounds__(256) void transpose_k(
    const float* __restrict__ in, float* __restrict__ out)
{
    __shared__ float t[32][33];
    const int b  = blockIdx.z;
    const int h0 = blockIdx.x * 32;
    const int j0 = blockIdx.y * 32;
    const int tx = threadIdx.x;     // 0..31
    const int ty = threadIdx.y;     // 0..7
    #pragma unroll
    for (int r = 0; r < 4; ++r) {
        int j = j0 + ty + r * 8;
        t[ty + r * 8][tx] = in[((long long)b * NN + j) * HH + h0 + tx];
    }
    __syncthreads();
    #pragma unroll
    for (int r = 0; r < 4; ++r) {
        int h = h0 + ty + r * 8;
        out[((long long)b * HH + h) * NN + j0 + tx] = t[tx][ty + r * 8];
    }
}

// ---------------------------------------------------------------------------
// Attention scores + leaky_relu + mask + softmax + *adj
// One block handles (b, i0..i0+1); thread j in [0,256).
// Lpb = left + ab1 (bias folded), rightT = [B,H,N].
// ---------------------------------------------------------------------------
__device__ __forceinline__ float block_max(float v, float* red)
{
    #pragma unroll
    for (int o = 32; o > 0; o >>= 1) v = fmaxf(v, __shfl_down(v, o));
    const int lane = threadIdx.x & 63, wid = threadIdx.x >> 6;
    if (lane == 0) red[wid] = v;
    __syncthreads();
    v = fmaxf(fmaxf(red[0], red[1]), fmaxf(red[2], red[3]));
    __syncthreads();
    return v;
}

__device__ __forceinline__ float block_sum(float v, float* red)
{
    #pragma unroll
    for (int o = 32; o > 0; o >>= 1) v += __shfl_down(v, o);
    const int lane = threadIdx.x & 63, wid = threadIdx.x >> 6;
    if (lane == 0) red[wid] = v;
    __syncthreads();
    v = red[0] + red[1] + red[2] + red[3];
    __syncthreads();
    return v;
}

__global__ __launch_bounds__(256) void attn_kernel(
    const float* __restrict__ Lpb,     // [B*N, H]
    const float* __restrict__ rightT,  // [B, H, N]
    const float* __restrict__ aW2,     // [H]
    const float* __restrict__ ab2,     // [1]
    const float* __restrict__ adj,     // [B, N, N]
    float* __restrict__ att)           // [B, N, N]
{
    __shared__ float sL[2][HH];
    __shared__ float sW[HH];
    __shared__ float red[4];

    const int b  = blockIdx.y;
    const int i0 = blockIdx.x * 2;
    const int j  = threadIdx.x;

    sW[j]    = aW2[j];
    sL[0][j] = Lpb[((long long)b * NN + i0    ) * HH + j];
    sL[1][j] = Lpb[((long long)b * NN + i0 + 1) * HH + j];
    __syncthreads();

    const float* rp = rightT + (long long)b * HH * NN + j;
    float acc0 = 0.f, acc1 = 0.f;
    for (int h = 0; h < HH; h += 8) {
        float r[8];
        #pragma unroll
        for (int u = 0; u < 8; ++u) r[u] = rp[(h + u) * NN];
        #pragma unroll
        for (int u = 0; u < 8; ++u) {
            float w = sW[h + u];
            acc0 += fmaxf(sL[0][h + u] + r[u], 0.f) * w;
            acc1 += fmaxf(sL[1][h + u] + r[u], 0.f) * w;
        }
    }

    const float ab2v = ab2[0];
    #pragma unroll
    for (int q = 0; q < 2; ++q) {
        float e = (q == 0 ? acc0 : acc1) + ab2v;
        e = (e > 0.f) ? e : 0.01f * e;                 // leaky_relu
        float a = adj[((long long)b * NN + i0 + q) * NN + j];
        float m = (a == 0.f) ? -1e9f : e;              // mask
        float mx = block_max(m, red);
        float p  = __expf(m - mx);
        float s  = block_sum(p, red);
        float o  = p / s * a;                          // softmax * adj
        att[((long long)b * NN + i0 + q) * NN + j] = o;
    }
}

// ---------------------------------------------------------------------------
// Launch
// ---------------------------------------------------------------------------
extern "C" void kernel_launch(void* const* d_in, const int* in_sizes, int n_in,
                              void* d_out, int out_size, void* d_ws, size_t ws_size,
                              hipStream_t stream)
{
    const float* feature = (const float*)d_in[0];
    const float* adj     = (const float*)d_in[1];
    const float* W0      = (const float*)d_in[2];
    const float* b0      = (const float*)d_in[3];
    const float* W1      = (const float*)d_in[4];
    const float* b1      = (const float*)d_in[5];
    const float* aW1     = (const float*)d_in[6];
    const float* ab1     = (const float*)d_in[7];
    const float* aW2     = (const float*)d_in[8];
    const float* ab2     = (const float*)d_in[9];
    float* out = (float*)d_out;
    float* ws  = (float*)d_ws;

    float* h    = ws;                       // 1024*600 = 614400
    float* Lpb  = h    + MROWS * DD;        // 1024*256 = 262144
    float* rraw = Lpb  + MROWS * HH;        // 262144
    float* rT   = rraw + MROWS * HH;        // 262144
    float* att  = rT   + MROWS * HH;        // 262144
    float* out1 = out;                      // layer-1 output staged in d_out

    const dim3 blk(256);
    for (int layer = 0; layer < 2; ++layer) {
        const float* x  = layer ? out1 : feature;
        const float* W  = layer ? W1 : W0;
        const float* bb = layer ? b1 : b0;
        float* o        = layer ? out : out1;

        // h = x @ W + b          [1024,600]
        gemm_f32<true, false><<<dim3((DD + BN - 1) / BN, MROWS / BM, 1), blk, 0, stream>>>(
            x, W, bb, h, MROWS, DD, DD, DD, 0, 0, 0);
        // Lpb = h @ aW1[:D] + ab1   [1024,256]
        gemm_f32<true, false><<<dim3(HH / BN, MROWS / BM, 1), blk, 0, stream>>>(
            h, aW1, ab1, Lpb, MROWS, HH, DD, HH, 0, 0, 0);
        // rraw = h @ aW1[D:]        [1024,256]
        gemm_f32<false, false><<<dim3(HH / BN, MROWS / BM, 1), blk, 0, stream>>>(
            h, aW1 + (long long)DD * HH, nullptr, rraw, MROWS, HH, DD, HH, 0, 0, 0);
        // rT = transpose(rraw)      [B,H,N]
        transpose_k<<<dim3(HH / 32, NN / 32, BATCH), dim3(32, 8), 0, stream>>>(rraw, rT);
        // att = softmax(mask(leaky(score))) * adj
        attn_kernel<<<dim3(NN / 2, BATCH), blk, 0, stream>>>(Lpb, rT, aW2, ab2, adj, att);
        // o = relu(att @ h)     batched [256,600]
        gemm_f32<false, true><<<dim3((DD + BN - 1) / BN, NN / BM, BATCH), blk, 0, stream>>>(
            att, h, nullptr, o, NN, DD, NN, DD,
            (long long)NN * NN, (long long)NN * DD, (long long)NN * DD);
    }
}

// Round 2
// 284.632 us; speedup vs baseline: 1.4244x; 1.4244x over previous
//
#include <hip/hip_runtime.h>
#include <hip/hip_bf16.h>

// ---------------------------------------------------------------------------
// Sizes (fixed for this problem)
// ---------------------------------------------------------------------------
#define BATCH 4
#define NN    256      // nodes
#define DD    600      // feature/mem dim
#define HH    256      // attn hidden
#define MROWS (BATCH*NN)   // 1024

// ---------------------------------------------------------------------------
// fp32 tiled GEMM: C = A[M,K] @ B[K,N] (+bias) (+relu), batched via z.
// 64x64 tile, 256 threads, 4x4 microtile. Split-B: cols >= nsplit come from
// B2 (column offset rebased) — used to fuse the left/right attn projections.
// ---------------------------------------------------------------------------
#define BMG 64
#define BNG 64
#define BKG 16
#define PAD 4

template<bool BIAS, bool RELU>
__global__ __launch_bounds__(256) void gemm64(
    const float* __restrict__ A, const float* __restrict__ B,
    const float* __restrict__ B2, const float* __restrict__ bias,
    float* __restrict__ C,
    int M, int N, int K, int lda, int ldb, int ldc,
    int Nb, int nsplit, int biasN,
    long long sA, long long sB, long long sC)
{
    __shared__ float As[BKG][BMG + PAD];   // k-major
    __shared__ float Bs[BKG][BNG + PAD];

    const int bz = blockIdx.z;
    const float* Ap = A + (long long)bz * sA;
    const int row0 = blockIdx.y * BMG;
    const int col0 = blockIdx.x * BNG;
    int cb = col0;
    const float* Bp = B;
    if (col0 >= nsplit) { Bp = B2; cb = col0 - nsplit; }
    Bp += (long long)bz * sB;
    float* Cp = C + (long long)bz * sC;

    const int tid = threadIdx.x;
    const int tx = tid & 15;          // N-dir (x4)
    const int ty = tid >> 4;          // M-dir (x4)

    const int am = tid >> 2;          // A-load row 0..63
    const int ak = (tid & 3) * 4;     // A-load k 0,4,8,12
    const int bk = tid >> 4;          // B-load k 0..15
    const int bc = (tid & 15) * 4;    // B-load col 0..60

    float acc[4][4] = {};

    for (int k0 = 0; k0 < K; k0 += BKG) {
        // ---- stage A tile (64 rows x 16 k), transposed into LDS ----
        {
            const int gr = row0 + am;
            const int gk = k0 + ak;
            float4 a;
            if (gk + 3 < K) {
                a = *(const float4*)&Ap[(long long)gr * lda + gk];
            } else {
                float* af = (float*)&a;
                #pragma unroll
                for (int u = 0; u < 4; ++u)
                    af[u] = (gk + u < K) ? Ap[(long long)gr * lda + gk + u] : 0.f;
            }
            As[ak + 0][am] = a.x;
            As[ak + 1][am] = a.y;
            As[ak + 2][am] = a.z;
            As[ak + 3][am] = a.w;
        }
        // ---- stage B tile (16 k x 64 cols) ----
        {
            const int gk = k0 + bk;
            const int gc = cb + bc;
            float4 b;
            if (gk < K && gc + 3 < Nb) {
                b = *(const float4*)&Bp[(long long)gk * ldb + gc];
            } else {
                float* bf = (float*)&b;
                #pragma unroll
                for (int u = 0; u < 4; ++u)
                    bf[u] = (gk < K && gc + u < Nb) ? Bp[(long long)gk * ldb + gc + u] : 0.f;
            }
            *(float4*)&Bs[bk][bc] = b;
        }
        __syncthreads();

        #pragma unroll
        for (int kk = 0; kk < BKG; ++kk) {
            float4 a = *(const float4*)&As[kk][ty * 4];
            float4 b = *(const float4*)&Bs[kk][tx * 4];
            const float* af = (const float*)&a;
            const float* bf = (const float*)&b;
            #pragma unroll
            for (int i = 0; i < 4; ++i)
                #pragma unroll
                for (int j = 0; j < 4; ++j)
                    acc[i][j] = fmaf(af[i], bf[j], acc[i][j]);
        }
        __syncthreads();
    }

    const bool doBias = BIAS && (col0 < biasN);
    #pragma unroll
    for (int i = 0; i < 4; ++i) {
        const int r = row0 + ty * 4 + i;
        const int c0 = col0 + tx * 4;
        if (r < M) {
            if (c0 + 3 < N) {
                float4 v = make_float4(acc[i][0], acc[i][1], acc[i][2], acc[i][3]);
                if (doBias) {
                    float4 bv = *(const float4*)&bias[c0];
                    v.x += bv.x; v.y += bv.y; v.z += bv.z; v.w += bv.w;
                }
                if (RELU) {
                    v.x = fmaxf(v.x, 0.f); v.y = fmaxf(v.y, 0.f);
                    v.z = fmaxf(v.z, 0.f); v.w = fmaxf(v.w, 0.f);
                }
                *(float4*)&Cp[(long long)r * ldc + c0] = v;
            } else {
                #pragma unroll
                for (int j = 0; j < 4; ++j) {
                    const int c = c0 + j;
                    if (c < N) {
                        float v = acc[i][j];
                        if (doBias) v += bias[c];
                        if (RELU) v = fmaxf(v, 0.f);
                        Cp[(long long)r * ldc + c] = v;
                    }
                }
            }
        }
    }
}

// ---------------------------------------------------------------------------
// Transpose right[B, N(j), ld=ldin] -> rightT[B, H, N(j)]
// ---------------------------------------------------------------------------
__global__ __launch_bounds__(256) void transpose_k(
    const float* __restrict__ in, float* __restrict__ out, int ldin)
{
    __shared__ float t[32][33];
    const int b  = blockIdx.z;
    const int h0 = blockIdx.x * 32;
    const int j0 = blockIdx.y * 32;
    const int tx = threadIdx.x;     // 0..31
    const int ty = threadIdx.y;     // 0..7
    #pragma unroll
    for (int r = 0; r < 4; ++r) {
        int j = j0 + ty + r * 8;
        t[ty + r * 8][tx] = in[((long long)b * NN + j) * ldin + h0 + tx];
    }
    __syncthreads();
    #pragma unroll
    for (int r = 0; r < 4; ++r) {
        int h = h0 + ty + r * 8;
        out[((long long)b * HH + h) * NN + j0 + tx] = t[tx][ty + r * 8];
    }
}

// ---------------------------------------------------------------------------
// Attention: score + leaky_relu + mask + softmax + *adj
// ---------------------------------------------------------------------------
__device__ __forceinline__ float block_max(float v, float* red)
{
    #pragma unroll
    for (int o = 32; o > 0; o >>= 1) v = fmaxf(v, __shfl_down(v, o));
    const int lane = threadIdx.x & 63, wid = threadIdx.x >> 6;
    if (lane == 0) red[wid] = v;
    __syncthreads();
    v = fmaxf(fmaxf(red[0], red[1]), fmaxf(red[2], red[3]));
    __syncthreads();
    return v;
}

__device__ __forceinline__ float block_sum(float v, float* red)
{
    #pragma unroll
    for (int o = 32; o > 0; o >>= 1) v += __shfl_down(v, o);
    const int lane = threadIdx.x & 63, wid = threadIdx.x >> 6;
    if (lane == 0) red[wid] = v;
    __syncthreads();
    v = red[0] + red[1] + red[2] + red[3];
    __syncthreads();
    return v;
}

__global__ __launch_bounds__(256) void attn_kernel(
    const float* __restrict__ Lpb,     // [B*N, ldl] (ab1 folded)
    const float* __restrict__ rightT,  // [B, H, N]
    const float* __restrict__ aW2,     // [H]
    const float* __restrict__ ab2,     // [1]
    const float* __restrict__ adj,     // [B, N, N]
    float* __restrict__ att,           // [B, N, N]
    int ldl)
{
    __shared__ float sL[2][HH];
    __shared__ float sW[HH];
    __shared__ float red[4];

    const int b  = blockIdx.y;
    const int i0 = blockIdx.x * 2;
    const int j  = threadIdx.x;

    sW[j]    = aW2[j];
    sL[0][j] = Lpb[((long long)b * NN + i0    ) * ldl + j];
    sL[1][j] = Lpb[((long long)b * NN + i0 + 1) * ldl + j];
    __syncthreads();

    const float* rp = rightT + (long long)b * HH * NN + j;
    float acc0 = 0.f, acc1 = 0.f;
    for (int h = 0; h < HH; h += 8) {
        float r[8];
        #pragma unroll
        for (int u = 0; u < 8; ++u) r[u] = rp[(h + u) * NN];
        #pragma unroll
        for (int u = 0; u < 8; ++u) {
            float w = sW[h + u];
            acc0 += fmaxf(sL[0][h + u] + r[u], 0.f) * w;
            acc1 += fmaxf(sL[1][h + u] + r[u], 0.f) * w;
        }
    }

    const float ab2v = ab2[0];
    #pragma unroll
    for (int q = 0; q < 2; ++q) {
        float e = (q == 0 ? acc0 : acc1) + ab2v;
        e = (e > 0.f) ? e : 0.01f * e;                 // leaky_relu
        float a = adj[((long long)b * NN + i0 + q) * NN + j];
        float m = (a == 0.f) ? -1e9f : e;              // mask
        float mx = block_max(m, red);
        float p  = __expf(m - mx);
        float s  = block_sum(p, red);
        float o  = p / s * a;                          // softmax * adj
        att[((long long)b * NN + i0 + q) * NN + j] = o;
    }
}

// ---------------------------------------------------------------------------
// Launch
// ---------------------------------------------------------------------------
extern "C" void kernel_launch(void* const* d_in, const int* in_sizes, int n_in,
                              void* d_out, int out_size, void* d_ws, size_t ws_size,
                              hipStream_t stream)
{
    const float* feature = (const float*)d_in[0];
    const float* adj     = (const float*)d_in[1];
    const float* W0      = (const float*)d_in[2];
    const float* b0      = (const float*)d_in[3];
    const float* W1      = (const float*)d_in[4];
    const float* b1      = (const float*)d_in[5];
    const float* aW1     = (const float*)d_in[6];
    const float* ab1     = (const float*)d_in[7];
    const float* aW2     = (const float*)d_in[8];
    const float* ab2     = (const float*)d_in[9];
    float* out = (float*)d_out;
    float* ws  = (float*)d_ws;

    float* h    = ws;                       // 1024*600
    float* LR   = h   + MROWS * DD;         // 1024*512 (left | right)
    float* rT   = LR  + MROWS * 512;        // 4*256*256
    float* att  = rT  + MROWS * HH;         // 4*256*256
    float* out1 = out;                      // layer-1 output staged in d_out

    const long long HUGE_SPLIT = 1 << 30;
    const dim3 blk(256);

    for (int layer = 0; layer < 2; ++layer) {
        const float* x  = layer ? out1 : feature;
        const float* W  = layer ? W1 : W0;
        const float* bb = layer ? b1 : b0;
        float* o        = layer ? out : out1;

        // h = x @ W + b          [1024,600]
        gemm64<true, false><<<dim3((DD + BNG - 1) / BNG, MROWS / BMG, 1), blk, 0, stream>>>(
            x, W, W, bb, h, MROWS, DD, DD, DD, DD, DD,
            DD, (int)HUGE_SPLIT, DD, 0, 0, 0);

        // LR = h @ [aW1[:D] | aW1[D:]] (+ab1 on left half)   [1024,512]
        gemm64<true, false><<<dim3(512 / BNG, MROWS / BMG, 1), blk, 0, stream>>>(
            h, aW1, aW1 + (long long)DD * HH, ab1, LR, MROWS, 512, DD, DD, HH, 512,
            HH, HH, HH, 0, 0, 0);

        // rT = transpose(LR[:,256:])      [B,H,N]
        transpose_k<<<dim3(HH / 32, NN / 32, BATCH), dim3(32, 8), 0, stream>>>(
            LR + HH, rT, 512);

        // att = softmax(mask(leaky(score))) * adj
        attn_kernel<<<dim3(NN / 2, BATCH), blk, 0, stream>>>(
            LR, rT, aW2, ab2, adj, att, 512);

        // o = relu(att @ h)     batched [256,600]
        gemm64<false, true><<<dim3((DD + BNG - 1) / BNG, NN / BMG, BATCH), blk, 0, stream>>>(
            att, h, h, nullptr, o, NN, DD, NN, NN, DD, DD,
            DD, (int)HUGE_SPLIT, 0,
            (long long)NN * NN, (long long)NN * DD, (long long)NN * DD);
    }
}

// Round 3
// 106.594 us; speedup vs baseline: 3.8036x; 2.6702x over previous
//
#include <hip/hip_runtime.h>
#include <hip/hip_bf16.h>

// ---------------------------------------------------------------------------
// Sizes (fixed)
// ---------------------------------------------------------------------------
#define BATCH 4
#define NN    256
#define DD    600
#define HH    256
#define MROWS (BATCH*NN)   // 1024
#define KPAD  640          // DD padded to multiple of 64

typedef __attribute__((ext_vector_type(8))) short bf16x8;   // 8 bf16 (4 VGPRs)
typedef __attribute__((ext_vector_type(4))) float f32x4;

__device__ __forceinline__ void gload16(const void* g, void* l)
{
    __builtin_amdgcn_global_load_lds(
        (const __attribute__((address_space(1))) void*)g,
        (__attribute__((address_space(3))) void*)l, 16, 0, 0);
}

// ---------------------------------------------------------------------------
// bf16 MFMA GEMM: C = A[M,K] @ B[K,N] (+bias cols<biasN) (+relu)
// A row-major [M][lda] bf16 ; BT row-major [N][ldb] bf16 (= B transposed).
// K multiple of 64. Tile 64x64x64, 256 threads = 4 waves (2x2), 32x32/wave.
// Outputs: fp32 (cols<Nvalid) and/or bf16 (all cols; pad cols get 0 naturally).
// LDS XOR-swizzle (T2/m201 pattern): linear global_load_lds dest + inverse-
// swizzled global source + swizzled ds_read_b128.
// ---------------------------------------------------------------------------
template<bool BIAS, bool RELU, bool WF32, bool WB16>
__global__ __launch_bounds__(256) void gemm_mfma(
    const __hip_bfloat16* __restrict__ A, const __hip_bfloat16* __restrict__ BT,
    const float* __restrict__ bias,
    float* __restrict__ Cf, __hip_bfloat16* __restrict__ Cb,
    int K, int lda, int ldb, int ldcf, int ldcb, int Nvalid, int biasN,
    long long sA, long long sBT, long long sCf, long long sCb)
{
    __shared__ __align__(16) char lds[16384];   // A: [0,8K)  B: [8K,16K)
    char* ldsA = lds;
    char* ldsB = lds + 8192;

    const int bz   = blockIdx.z;
    const int tid  = threadIdx.x;
    const int lane = tid & 63;
    const int wid  = tid >> 6;
    const int wr   = wid >> 1;          // wave row 0..1  (32 rows each)
    const int wc   = wid & 1;           // wave col 0..1  (32 cols each)
    const int row0 = blockIdx.y * 64;
    const int col0 = blockIdx.x * 64;

    const char* Ab = (const char*)A + (bz * sA + (long long)row0 * lda) * 2;
    const char* Bb = (const char*)BT + (bz * sBT + (long long)col0 * ldb) * 2;

    // staging: issue i covers LDS bytes [i*4096 + tid*16, +16)
    //   -> LDS row r = tid/8 + i*32, colbyte = (tid%8)*16
    // inverse-swizzle the SOURCE column so swizzled reads see correct data
    const int sr   = tid >> 3;                    // 0..31
    const int scb  = (tid & 7) * 16;              // 0..112
    const int scbs = scb ^ ((sr & 7) << 4);       // (r&7) invariant to +32

    const char* gA0 = Ab + (long long)sr        * (lda * 2) + scbs;
    const char* gA1 = Ab + (long long)(sr + 32) * (lda * 2) + scbs;
    const char* gB0 = Bb + (long long)sr        * (ldb * 2) + scbs;
    const char* gB1 = Bb + (long long)(sr + 32) * (ldb * 2) + scbs;

    char* dA0 = ldsA + wid * 1024;
    char* dA1 = ldsA + 4096 + wid * 1024;
    char* dB0 = ldsB + wid * 1024;
    char* dB1 = ldsB + 4096 + wid * 1024;

    f32x4 acc[2][2] = {};

    // fragment read addressing: lane holds row (lane&15), k-bytes (lane>>4)*16
    const int fr = lane & 15;
    const int kg = (lane >> 4) * 16;
    const int xv = (fr & 7) << 4;       // XOR swizzle for frag rows

    const int nk = K >> 6;
    for (int t = 0; t < nk; ++t) {
        gload16(gA0, dA0); gload16(gA1, dA1);
        gload16(gB0, dB0); gload16(gB1, dB1);
        gA0 += 128; gA1 += 128; gB0 += 128; gB1 += 128;
        __syncthreads();                 // drains vmcnt -> LDS tile ready
        #pragma unroll
        for (int ks = 0; ks < 2; ++ks) {
            const int kb = ks * 64 + kg;
            bf16x8 a0 = *(const bf16x8*)(ldsA + (wr * 32 + fr)      * 128 + (kb ^ xv));
            bf16x8 a1 = *(const bf16x8*)(ldsA + (wr * 32 + 16 + fr) * 128 + (kb ^ xv));
            bf16x8 b0 = *(const bf16x8*)(ldsB + (wc * 32 + fr)      * 128 + (kb ^ xv));
            bf16x8 b1 = *(const bf16x8*)(ldsB + (wc * 32 + 16 + fr) * 128 + (kb ^ xv));
            acc[0][0] = __builtin_amdgcn_mfma_f32_16x16x32_bf16(a0, b0, acc[0][0], 0, 0, 0);
            acc[0][1] = __builtin_amdgcn_mfma_f32_16x16x32_bf16(a0, b1, acc[0][1], 0, 0, 0);
            acc[1][0] = __builtin_amdgcn_mfma_f32_16x16x32_bf16(a1, b0, acc[1][0], 0, 0, 0);
            acc[1][1] = __builtin_amdgcn_mfma_f32_16x16x32_bf16(a1, b1, acc[1][1], 0, 0, 0);
        }
        __syncthreads();                 // protect LDS before next stage
    }

    // epilogue: C/D frag mapping col=lane&15, row=(lane>>4)*4+reg
    const int er = (lane >> 4) * 4;
    const int ec = lane & 15;
    #pragma unroll
    for (int mi = 0; mi < 2; ++mi) {
        #pragma unroll
        for (int ni = 0; ni < 2; ++ni) {
            const int gr = row0 + wr * 32 + mi * 16 + er;
            const int gc = col0 + wc * 32 + ni * 16 + ec;
            const float bv = (BIAS && gc < biasN) ? bias[gc] : 0.f;
            #pragma unroll
            for (int r = 0; r < 4; ++r) {
                float v = acc[mi][ni][r] + bv;
                if (RELU) v = fmaxf(v, 0.f);
                const long long row = gr + r;
                if (WF32 && gc < Nvalid)
                    Cf[bz * sCf + row * ldcf + gc] = v;
                if (WB16)
                    Cb[bz * sCb + row * ldcb + gc] = __float2bfloat16(v);
            }
        }
    }
}

// ---------------------------------------------------------------------------
// Prep: bf16 conversions + transposes (one launch).
//  xb  [1024][640]  = pad(feature)
//  W0T [640][640]   = W0^T zero-padded
//  W1T [640][640]   = W1^T zero-padded
//  aW1T[512][640]   : rows 0..255 = aW1[:600]^T (left), 256..511 = aW1[600:]^T
// ---------------------------------------------------------------------------
__global__ __launch_bounds__(256) void prep_kernel(
    const float* __restrict__ feature, const float* __restrict__ W0,
    const float* __restrict__ W1, const float* __restrict__ aW1,
    __hip_bfloat16* __restrict__ xb, __hip_bfloat16* __restrict__ W0T,
    __hip_bfloat16* __restrict__ W1T, __hip_bfloat16* __restrict__ aW1T)
{
    const int bid = blockIdx.x;
    const int tid = threadIdx.x;
    if (bid < 2560) {                          // xb
        int idx = bid * 256 + tid;
        int r = idx / KPAD, c = idx % KPAD;
        float v = (c < DD) ? feature[r * DD + c] : 0.f;
        xb[idx] = __float2bfloat16(v);
    } else if (bid < 2560 + 1600) {            // W0T
        int idx = (bid - 2560) * 256 + tid;
        int n = idx / KPAD, k = idx % KPAD;
        float v = (n < DD && k < DD) ? W0[k * DD + n] : 0.f;
        W0T[idx] = __float2bfloat16(v);
    } else if (bid < 2560 + 3200) {            // W1T
        int idx = (bid - 4160) * 256 + tid;
        int n = idx / KPAD, k = idx % KPAD;
        float v = (n < DD && k < DD) ? W1[k * DD + n] : 0.f;
        W1T[idx] = __float2bfloat16(v);
    } else {                                   // aW1T
        int idx = (bid - 5760) * 256 + tid;
        int n = idx / KPAD, k = idx % KPAD;
        float v = 0.f;
        if (k < DD) v = (n < HH) ? aW1[k * HH + n] : aW1[(DD + k) * HH + (n - HH)];
        aW1T[idx] = __float2bfloat16(v);
    }
}

// ---------------------------------------------------------------------------
// hT[b][d][j] = h[b*256+j][d]   (bf16 32x32 LDS tile transpose)
// ---------------------------------------------------------------------------
__global__ __launch_bounds__(256) void transpose_h(
    const __hip_bfloat16* __restrict__ h, __hip_bfloat16* __restrict__ hT)
{
    __shared__ __hip_bfloat16 t[32][33];
    const int b  = blockIdx.z;
    const int d0 = blockIdx.x * 32;
    const int j0 = blockIdx.y * 32;
    const int tx = threadIdx.x;   // 0..31
    const int ty = threadIdx.y;   // 0..7
    #pragma unroll
    for (int r = 0; r < 4; ++r)
        t[ty + r * 8][tx] = h[((long long)(b * NN + j0 + ty + r * 8)) * KPAD + d0 + tx];
    __syncthreads();
    #pragma unroll
    for (int r = 0; r < 4; ++r)
        hT[((long long)b * KPAD + d0 + ty + r * 8) * NN + j0 + tx] = t[tx][ty + r * 8];
}

// ---------------------------------------------------------------------------
// Attention: score + leaky_relu + mask + softmax + *adj  -> att (bf16)
// LR[B*N][512]: cols 0..255 = left+ab1, cols 256..511 = right.
// Block = (b, rows i0..i0+1); thread j. right rows read per-thread (L2-res).
// ---------------------------------------------------------------------------
__device__ __forceinline__ float block_max(float v, float* red)
{
    #pragma unroll
    for (int o = 32; o > 0; o >>= 1) v = fmaxf(v, __shfl_down(v, o));
    const int lane = threadIdx.x & 63, w = threadIdx.x >> 6;
    if (lane == 0) red[w] = v;
    __syncthreads();
    v = fmaxf(fmaxf(red[0], red[1]), fmaxf(red[2], red[3]));
    __syncthreads();
    return v;
}

__device__ __forceinline__ float block_sum(float v, float* red)
{
    #pragma unroll
    for (int o = 32; o > 0; o >>= 1) v += __shfl_down(v, o);
    const int lane = threadIdx.x & 63, w = threadIdx.x >> 6;
    if (lane == 0) red[w] = v;
    __syncthreads();
    v = red[0] + red[1] + red[2] + red[3];
    __syncthreads();
    return v;
}

__global__ __launch_bounds__(256) void attn_kernel(
    const float* __restrict__ LR, const float* __restrict__ aW2,
    const float* __restrict__ ab2, const float* __restrict__ adj,
    __hip_bfloat16* __restrict__ att)
{
    __shared__ float sL[2][HH];
    __shared__ float sW[HH];
    __shared__ float red[4];

    const int b  = blockIdx.y;
    const int i0 = blockIdx.x * 2;
    const int j  = threadIdx.x;

    sW[j]    = aW2[j];
    sL[0][j] = LR[((long long)(b * NN + i0)) * 512 + j];
    sL[1][j] = LR[((long long)(b * NN + i0 + 1)) * 512 + j];
    __syncthreads();

    const float* rp = LR + ((long long)(b * NN + j)) * 512 + HH;
    float acc0 = 0.f, acc1 = 0.f;
    for (int h = 0; h < HH; h += 8) {
        float4 ra = *(const float4*)(rp + h);
        float4 rb = *(const float4*)(rp + h + 4);
        float rv[8] = {ra.x, ra.y, ra.z, ra.w, rb.x, rb.y, rb.z, rb.w};
        #pragma unroll
        for (int u = 0; u < 8; ++u) {
            const float w = sW[h + u];
            acc0 += fmaxf(sL[0][h + u] + rv[u], 0.f) * w;
            acc1 += fmaxf(sL[1][h + u] + rv[u], 0.f) * w;
        }
    }

    const float ab2v = ab2[0];
    #pragma unroll
    for (int q = 0; q < 2; ++q) {
        float e = (q == 0 ? acc0 : acc1) + ab2v;
        e = (e > 0.f) ? e : 0.01f * e;                       // leaky_relu
        const float a = adj[((long long)(b * NN + i0 + q)) * NN + j];
        const float m = (a == 0.f) ? -1e9f : e;              // mask
        const float mx = block_max(m, red);
        const float p  = __expf(m - mx);
        const float s  = block_sum(p, red);
        att[((long long)(b * NN + i0 + q)) * NN + j] = __float2bfloat16(p / s * a);
    }
}

// ---------------------------------------------------------------------------
// Launch
// ---------------------------------------------------------------------------
extern "C" void kernel_launch(void* const* d_in, const int* in_sizes, int n_in,
                              void* d_out, int out_size, void* d_ws, size_t ws_size,
                              hipStream_t stream)
{
    const float* feature = (const float*)d_in[0];
    const float* adj     = (const float*)d_in[1];
    const float* W0      = (const float*)d_in[2];
    const float* b0      = (const float*)d_in[3];
    const float* W1      = (const float*)d_in[4];
    const float* b1      = (const float*)d_in[5];
    const float* aW1     = (const float*)d_in[6];
    const float* ab1     = (const float*)d_in[7];
    const float* aW2     = (const float*)d_in[8];
    const float* ab2     = (const float*)d_in[9];
    float* out = (float*)d_out;

    // ws carve (bf16 region first, then fp32)
    __hip_bfloat16* bw = (__hip_bfloat16*)d_ws;
    __hip_bfloat16* xb   = bw;                       // 1024*640
    __hip_bfloat16* W0T  = xb   + MROWS * KPAD;      // 640*640
    __hip_bfloat16* W1T  = W0T  + KPAD * KPAD;       // 640*640
    __hip_bfloat16* aW1T = W1T  + KPAD * KPAD;       // 512*640
    __hip_bfloat16* hb   = aW1T + 512 * KPAD;        // 1024*640
    __hip_bfloat16* hT   = hb   + MROWS * KPAD;      // 4*640*256
    __hip_bfloat16* att  = hT   + BATCH * KPAD * NN; // 4*256*256
    float* LR = (float*)(att + BATCH * NN * NN);     // 1024*512 fp32

    prep_kernel<<<7040, 256, 0, stream>>>(feature, W0, W1, aW1, xb, W0T, W1T, aW1T);

    for (int layer = 0; layer < 2; ++layer) {
        const __hip_bfloat16* WT = layer ? W1T : W0T;
        const float* bb          = layer ? b1 : b0;

        // hb = x @ W + b   [1024][640] bf16
        gemm_mfma<true, false, false, true><<<dim3(KPAD / 64, MROWS / 64, 1), 256, 0, stream>>>(
            xb, WT, bb, nullptr, hb,
            KPAD, KPAD, KPAD, 0, KPAD, DD, DD, 0, 0, 0, 0);

        // hT[b][d][j]
        transpose_h<<<dim3(KPAD / 32, NN / 32, BATCH), dim3(32, 8), 0, stream>>>(hb, hT);

        // LR = hb @ aW1T^T (+ab1 on cols<256)   [1024][512] fp32
        gemm_mfma<true, false, true, false><<<dim3(512 / 64, MROWS / 64, 1), 256, 0, stream>>>(
            hb, aW1T, ab1, LR, nullptr,
            KPAD, KPAD, KPAD, 512, 0, 512, HH, 0, 0, 0, 0);

        // att = softmax(mask(leaky(score))) * adj   bf16
        attn_kernel<<<dim3(NN / 2, BATCH), 256, 0, stream>>>(LR, aW2, ab2, adj, att);

        // out = relu(att @ h): layer0 -> xb (bf16, layer-2 input); layer1 -> out fp32
        if (layer == 0) {
            gemm_mfma<false, true, false, true><<<dim3(KPAD / 64, NN / 64, BATCH), 256, 0, stream>>>(
                att, hT, nullptr, nullptr, xb,
                NN, NN, NN, 0, KPAD, DD, 0,
                (long long)NN * NN, (long long)KPAD * NN, 0, (long long)NN * KPAD);
        } else {
            gemm_mfma<false, true, true, false><<<dim3(KPAD / 64, NN / 64, BATCH), 256, 0, stream>>>(
                att, hT, nullptr, out, nullptr,
                NN, NN, NN, DD, 0, DD, 0,
                (long long)NN * NN, (long long)KPAD * NN, (long long)NN * DD, 0);
        }
    }
}

// Round 4
// 86.956 us; speedup vs baseline: 4.6626x; 1.2258x over previous
//
#include <hip/hip_runtime.h>
#include <hip/hip_bf16.h>

// ---------------------------------------------------------------------------
// Sizes (fixed)
// ---------------------------------------------------------------------------
#define BATCH 4
#define NN    256
#define DD    600
#define HH    256
#define MROWS (BATCH*NN)   // 1024
#define KPAD  640          // DD padded to multiple of 64

typedef __attribute__((ext_vector_type(8))) short bf16x8;   // 8 bf16 (4 VGPRs)
typedef __attribute__((ext_vector_type(4))) float f32x4;

__device__ __forceinline__ void gload16(const void* g, void* l)
{
    __builtin_amdgcn_global_load_lds(
        (const __attribute__((address_space(1))) void*)g,
        (__attribute__((address_space(3))) void*)l, 16, 0, 0);
}

// ---------------------------------------------------------------------------
// bf16 MFMA GEMM: C = A[M,K] @ B[K,N] (+bias cols<biasN) (+relu)
// A row-major [M][lda] bf16 ; BT row-major [N][ldb] bf16 (= B transposed).
// K multiple of 64. Tile 64x64x64, 256 threads = 4 waves (2x2), 32x32/wave.
// WF32: fp32 C (cols<Nvalid).  WB16: bf16 C (all cols).
// WHT:  also write hT[b][d][j] (d=col, j=row%256, b=row/256) via LDS retile.
// LDS XOR-swizzle (T2/m201): linear global_load_lds dest + inverse-swizzled
// global source + swizzled ds_read_b128.
// ---------------------------------------------------------------------------
template<bool BIAS, bool RELU, bool WF32, bool WB16, bool WHT>
__global__ __launch_bounds__(256) void gemm_mfma(
    const __hip_bfloat16* __restrict__ A, const __hip_bfloat16* __restrict__ BT,
    const float* __restrict__ bias,
    float* __restrict__ Cf, __hip_bfloat16* __restrict__ Cb,
    __hip_bfloat16* __restrict__ hT,
    int K, int lda, int ldb, int ldcf, int ldcb, int Nvalid, int biasN,
    long long sA, long long sBT, long long sCf, long long sCb)
{
    __shared__ __align__(16) char lds[16384];   // A: [0,8K)  B: [8K,16K)
    char* ldsA = lds;
    char* ldsB = lds + 8192;

    const int bz   = blockIdx.z;
    const int tid  = threadIdx.x;
    const int lane = tid & 63;
    const int wid  = tid >> 6;
    const int wr   = wid >> 1;          // wave row 0..1  (32 rows each)
    const int wc   = wid & 1;           // wave col 0..1  (32 cols each)
    const int row0 = blockIdx.y * 64;
    const int col0 = blockIdx.x * 64;

    const char* Ab = (const char*)A + (bz * sA + (long long)row0 * lda) * 2;
    const char* Bb = (const char*)BT + (bz * sBT + (long long)col0 * ldb) * 2;

    // staging: issue i covers LDS bytes [i*4096 + tid*16, +16)
    const int sr   = tid >> 3;                    // 0..31
    const int scb  = (tid & 7) * 16;              // 0..112
    const int scbs = scb ^ ((sr & 7) << 4);       // inverse source swizzle

    const char* gA0 = Ab + (long long)sr        * (lda * 2) + scbs;
    const char* gA1 = Ab + (long long)(sr + 32) * (lda * 2) + scbs;
    const char* gB0 = Bb + (long long)sr        * (ldb * 2) + scbs;
    const char* gB1 = Bb + (long long)(sr + 32) * (ldb * 2) + scbs;

    char* dA0 = ldsA + wid * 1024;
    char* dA1 = ldsA + 4096 + wid * 1024;
    char* dB0 = ldsB + wid * 1024;
    char* dB1 = ldsB + 4096 + wid * 1024;

    f32x4 acc[2][2] = {};

    const int fr = lane & 15;
    const int kg = (lane >> 4) * 16;
    const int xv = (fr & 7) << 4;       // read-side XOR swizzle

    const int nk = K >> 6;
    for (int t = 0; t < nk; ++t) {
        gload16(gA0, dA0); gload16(gA1, dA1);
        gload16(gB0, dB0); gload16(gB1, dB1);
        gA0 += 128; gA1 += 128; gB0 += 128; gB1 += 128;
        __syncthreads();
        #pragma unroll
        for (int ks = 0; ks < 2; ++ks) {
            const int kb = ks * 64 + kg;
            bf16x8 a0 = *(const bf16x8*)(ldsA + (wr * 32 + fr)      * 128 + (kb ^ xv));
            bf16x8 a1 = *(const bf16x8*)(ldsA + (wr * 32 + 16 + fr) * 128 + (kb ^ xv));
            bf16x8 b0 = *(const bf16x8*)(ldsB + (wc * 32 + fr)      * 128 + (kb ^ xv));
            bf16x8 b1 = *(const bf16x8*)(ldsB + (wc * 32 + 16 + fr) * 128 + (kb ^ xv));
            acc[0][0] = __builtin_amdgcn_mfma_f32_16x16x32_bf16(a0, b0, acc[0][0], 0, 0, 0);
            acc[0][1] = __builtin_amdgcn_mfma_f32_16x16x32_bf16(a0, b1, acc[0][1], 0, 0, 0);
            acc[1][0] = __builtin_amdgcn_mfma_f32_16x16x32_bf16(a1, b0, acc[1][0], 0, 0, 0);
            acc[1][1] = __builtin_amdgcn_mfma_f32_16x16x32_bf16(a1, b1, acc[1][1], 0, 0, 0);
        }
        __syncthreads();
    }

    // epilogue: C/D frag mapping col=lane&15, row=(lane>>4)*4+reg
    const int er = (lane >> 4) * 4;
    const int ec = lane & 15;
    __hip_bfloat16* sT = (__hip_bfloat16*)lds;   // [64][72] retile buffer

    #pragma unroll
    for (int mi = 0; mi < 2; ++mi) {
        #pragma unroll
        for (int ni = 0; ni < 2; ++ni) {
            const int lr0 = wr * 32 + mi * 16 + er;
            const int lc  = wc * 32 + ni * 16 + ec;
            const int gr = row0 + lr0;
            const int gc = col0 + lc;
            const float bv = (BIAS && gc < biasN) ? bias[gc] : 0.f;
            #pragma unroll
            for (int r = 0; r < 4; ++r) {
                float v = acc[mi][ni][r] + bv;
                if (RELU) v = fmaxf(v, 0.f);
                const __hip_bfloat16 hv = __float2bfloat16(v);
                const long long row = gr + r;
                if (WF32 && gc < Nvalid)
                    Cf[bz * sCf + row * ldcf + gc] = v;
                if (WB16)
                    Cb[bz * sCb + row * ldcb + gc] = hv;
                if (WHT)
                    sT[(lr0 + r) * 72 + lc] = hv;
            }
        }
    }

    if (WHT) {
        __syncthreads();
        const int b  = row0 >> 8;        // M==1024 rows = b*256 + i
        const int i0 = row0 & 255;
        const int cc = tid >> 3;         // 0..31 (d within tile, 2 passes)
        const int ch = tid & 7;          // j-chunk of 8
        #pragma unroll
        for (int p = 0; p < 2; ++p) {
            const int d = col0 + cc + p * 32;
            __align__(16) __hip_bfloat16 tmp[8];
            #pragma unroll
            for (int u = 0; u < 8; ++u)
                tmp[u] = sT[(ch * 8 + u) * 72 + cc + p * 32];
            *(float4*)&hT[((long long)b * KPAD + d) * NN + i0 + ch * 8] = *(float4*)tmp;
        }
    }
}

// ---------------------------------------------------------------------------
// Prep: xb = bf16(pad(feature)) vectorized; W0T/W1T/aW1T via 32x32 LDS
// tile transpose (coalesced both sides) + bf16 convert.
//  blocks 0..639      : xb   (4 elems/thread)
//  blocks 640..1039   : W0T [640n][640k]
//  blocks 1040..1439  : W1T
//  blocks 1440..1759  : aW1T[512n][640k] (n<256 left cols, else right)
// ---------------------------------------------------------------------------
__global__ __launch_bounds__(256) void prep_kernel(
    const float* __restrict__ feature, const float* __restrict__ W0,
    const float* __restrict__ W1, const float* __restrict__ aW1,
    __hip_bfloat16* __restrict__ xb, __hip_bfloat16* __restrict__ W0T,
    __hip_bfloat16* __restrict__ W1T, __hip_bfloat16* __restrict__ aW1T)
{
    const int bid = blockIdx.x;
    const int tid = threadIdx.x;
    if (bid < 640) {
        const int idx = (bid * 256 + tid) * 4;
        const int r = idx / KPAD, c = idx % KPAD;
        float4 v = make_float4(0.f, 0.f, 0.f, 0.f);
        if (c < DD) v = *(const float4*)&feature[r * DD + c];   // DD%4==0
        __align__(8) __hip_bfloat16 o[4] = {
            __float2bfloat16(v.x), __float2bfloat16(v.y),
            __float2bfloat16(v.z), __float2bfloat16(v.w)};
        *(float2*)&xb[idx] = *(float2*)o;
        return;
    }
    __shared__ float tile[32][33];
    const int t = bid - 640;
    const int which = (t < 400) ? 0 : (t < 800) ? 1 : 2;
    const int tt = (which == 0) ? t : (which == 1) ? t - 400 : t - 800;
    const int n0 = (tt / 20) * 32;
    const int k0 = (tt % 20) * 32;
    const int tx = tid & 31, ty = tid >> 5;
    #pragma unroll
    for (int r = 0; r < 4; ++r) {
        const int k = k0 + ty + r * 8;
        const int n = n0 + tx;
        float v = 0.f;
        if (which == 0)      { if (k < DD && n < DD) v = W0[k * DD + n]; }
        else if (which == 1) { if (k < DD && n < DD) v = W1[k * DD + n]; }
        else                 { if (k < DD) v = (n < HH) ? aW1[k * HH + n]
                                                        : aW1[(DD + k) * HH + (n - HH)]; }
        tile[ty + r * 8][tx] = v;
    }
    __syncthreads();
    __hip_bfloat16* dst = (which == 0) ? W0T : (which == 1) ? W1T : aW1T;
    #pragma unroll
    for (int r = 0; r < 4; ++r) {
        const int n = n0 + ty + r * 8;
        const int k = k0 + tx;
        dst[n * KPAD + k] = __float2bfloat16(tile[tx][ty + r * 8]);
    }
}

// ---------------------------------------------------------------------------
// Attention: score + leaky_relu + mask + softmax + *adj -> att (bf16)
// LR[B*N][512] fp32: cols 0..255 left+ab1, 256..511 right.
// Block = (b, 4 rows i0..i0+3); thread j. 256 blocks (1/CU).
// 4-row softmax reductions interleaved (one LDS round each).
// ---------------------------------------------------------------------------
__device__ __forceinline__ void block_max4(float* v, float (*red)[4])
{
    #pragma unroll
    for (int o = 32; o > 0; o >>= 1)
        #pragma unroll
        for (int q = 0; q < 4; ++q) v[q] = fmaxf(v[q], __shfl_down(v[q], o));
    const int lane = threadIdx.x & 63, w = threadIdx.x >> 6;
    if (lane == 0) { red[w][0]=v[0]; red[w][1]=v[1]; red[w][2]=v[2]; red[w][3]=v[3]; }
    __syncthreads();
    #pragma unroll
    for (int q = 0; q < 4; ++q)
        v[q] = fmaxf(fmaxf(red[0][q], red[1][q]), fmaxf(red[2][q], red[3][q]));
    __syncthreads();
}

__device__ __forceinline__ void block_sum4(float* v, float (*red)[4])
{
    #pragma unroll
    for (int o = 32; o > 0; o >>= 1)
        #pragma unroll
        for (int q = 0; q < 4; ++q) v[q] += __shfl_down(v[q], o);
    const int lane = threadIdx.x & 63, w = threadIdx.x >> 6;
    if (lane == 0) { red[w][0]=v[0]; red[w][1]=v[1]; red[w][2]=v[2]; red[w][3]=v[3]; }
    __syncthreads();
    #pragma unroll
    for (int q = 0; q < 4; ++q)
        v[q] = red[0][q] + red[1][q] + red[2][q] + red[3][q];
    __syncthreads();
}

__global__ __launch_bounds__(256) void attn_kernel(
    const float* __restrict__ LR, const float* __restrict__ aW2,
    const float* __restrict__ ab2, const float* __restrict__ adj,
    __hip_bfloat16* __restrict__ att)
{
    __shared__ float sL[4][HH];
    __shared__ float sW[HH];
    __shared__ float red[4][4];

    const int b  = blockIdx.y;
    const int i0 = blockIdx.x * 4;
    const int j  = threadIdx.x;

    sW[j] = aW2[j];
    #pragma unroll
    for (int q = 0; q < 4; ++q)
        sL[q][j] = LR[((long long)(b * NN + i0 + q)) * 512 + j];
    __syncthreads();

    const float* rp = LR + ((long long)(b * NN + j)) * 512 + HH;
    float acc[4] = {0.f, 0.f, 0.f, 0.f};
    for (int h = 0; h < HH; h += 8) {
        const float4 ra = *(const float4*)(rp + h);
        const float4 rb = *(const float4*)(rp + h + 4);
        const float4 w0 = *(const float4*)&sW[h];
        const float4 w1 = *(const float4*)&sW[h + 4];
        #pragma unroll
        for (int q = 0; q < 4; ++q) {
            const float4 l0 = *(const float4*)&sL[q][h];
            const float4 l1 = *(const float4*)&sL[q][h + 4];
            float s = fmaxf(l0.x + ra.x, 0.f) * w0.x;
            s += fmaxf(l0.y + ra.y, 0.f) * w0.y;
            s += fmaxf(l0.z + ra.z, 0.f) * w0.z;
            s += fmaxf(l0.w + ra.w, 0.f) * w0.w;
            s += fmaxf(l1.x + rb.x, 0.f) * w1.x;
            s += fmaxf(l1.y + rb.y, 0.f) * w1.y;
            s += fmaxf(l1.z + rb.z, 0.f) * w1.z;
            s += fmaxf(l1.w + rb.w, 0.f) * w1.w;
            acc[q] += s;
        }
    }

    const float ab2v = ab2[0];
    float m[4], a[4];
    #pragma unroll
    for (int q = 0; q < 4; ++q) {
        float e = acc[q] + ab2v;
        e = (e > 0.f) ? e : 0.01f * e;                       // leaky_relu
        a[q] = adj[((long long)(b * NN + i0 + q)) * NN + j];
        m[q] = (a[q] == 0.f) ? -1e9f : e;                    // mask
    }
    float mx[4] = {m[0], m[1], m[2], m[3]};
    block_max4(mx, red);
    float p[4];
    #pragma unroll
    for (int q = 0; q < 4; ++q) p[q] = __expf(m[q] - mx[q]);
    float s[4] = {p[0], p[1], p[2], p[3]};
    block_sum4(s, red);
    #pragma unroll
    for (int q = 0; q < 4; ++q)
        att[((long long)(b * NN + i0 + q)) * NN + j] = __float2bfloat16(p[q] / s[q] * a[q]);
}

// ---------------------------------------------------------------------------
// Launch
// ---------------------------------------------------------------------------
extern "C" void kernel_launch(void* const* d_in, const int* in_sizes, int n_in,
                              void* d_out, int out_size, void* d_ws, size_t ws_size,
                              hipStream_t stream)
{
    const float* feature = (const float*)d_in[0];
    const float* adj     = (const float*)d_in[1];
    const float* W0      = (const float*)d_in[2];
    const float* b0      = (const float*)d_in[3];
    const float* W1      = (const float*)d_in[4];
    const float* b1      = (const float*)d_in[5];
    const float* aW1     = (const float*)d_in[6];
    const float* ab1     = (const float*)d_in[7];
    const float* aW2     = (const float*)d_in[8];
    const float* ab2     = (const float*)d_in[9];
    float* out = (float*)d_out;

    __hip_bfloat16* bw = (__hip_bfloat16*)d_ws;
    __hip_bfloat16* xb   = bw;                       // 1024*640
    __hip_bfloat16* W0T  = xb   + MROWS * KPAD;      // 640*640
    __hip_bfloat16* W1T  = W0T  + KPAD * KPAD;       // 640*640
    __hip_bfloat16* aW1T = W1T  + KPAD * KPAD;       // 512*640
    __hip_bfloat16* hb   = aW1T + 512 * KPAD;        // 1024*640
    __hip_bfloat16* hT   = hb   + MROWS * KPAD;      // 4*640*256
    __hip_bfloat16* att  = hT   + BATCH * KPAD * NN; // 4*256*256
    float* LR = (float*)(att + BATCH * NN * NN);     // 1024*512 fp32

    prep_kernel<<<1760, 256, 0, stream>>>(feature, W0, W1, aW1, xb, W0T, W1T, aW1T);

    for (int layer = 0; layer < 2; ++layer) {
        const __hip_bfloat16* WT = layer ? W1T : W0T;
        const float* bb          = layer ? b1 : b0;

        // hb = x @ W + b  [1024][640] bf16 ; also hT[b][d][j]
        gemm_mfma<true, false, false, true, true><<<dim3(KPAD / 64, MROWS / 64, 1), 256, 0, stream>>>(
            xb, WT, bb, nullptr, hb, hT,
            KPAD, KPAD, KPAD, 0, KPAD, DD, DD, 0, 0, 0, 0);

        // LR = hb @ aW1T^T (+ab1 on cols<256)   [1024][512] fp32
        gemm_mfma<true, false, true, false, false><<<dim3(512 / 64, MROWS / 64, 1), 256, 0, stream>>>(
            hb, aW1T, ab1, LR, nullptr, nullptr,
            KPAD, KPAD, KPAD, 512, 0, 512, HH, 0, 0, 0, 0);

        // att = softmax(mask(leaky(score))) * adj   bf16
        attn_kernel<<<dim3(NN / 4, BATCH), 256, 0, stream>>>(LR, aW2, ab2, adj, att);

        // out = relu(att @ h): layer0 -> xb (bf16); layer1 -> out fp32
        if (layer == 0) {
            gemm_mfma<false, true, false, true, false><<<dim3(KPAD / 64, NN / 64, BATCH), 256, 0, stream>>>(
                att, hT, nullptr, nullptr, xb, nullptr,
                NN, NN, NN, 0, KPAD, DD, 0,
                (long long)NN * NN, (long long)KPAD * NN, 0, (long long)NN * KPAD);
        } else {
            gemm_mfma<false, true, true, false, false><<<dim3(KPAD / 64, NN / 64, BATCH), 256, 0, stream>>>(
                att, hT, nullptr, out, nullptr, nullptr,
                NN, NN, NN, DD, 0, DD, 0,
                (long long)NN * NN, (long long)KPAD * NN, (long long)NN * DD, 0);
        }
    }
}